// Round 12
// baseline (1675.774 us; speedup 1.0000x reference)
//
#include <hip/hip_runtime.h>
#include <math.h>

// ---------------------------------------------------------------------------
// SpatioTemporalOutageModel:
//   GCN(14->64) -> GCN(64->64)+county_bias -> LSTM(64->128, T=336) -> MLP(128->64->1)
//
// R12 (LSTM: ping-pong weight stream -- defeat LICM, get GEMM-style pipelining):
//  - R3-R11 post-mortem: weight loads are loop-INVARIANT -> LICM hoists them,
//    allocator refuses the 96-reg live range across the barriered loop and
//    rematerializes them as a SERIALIZED trickle of reloads each step
//    (~20 exposed L2 latencies = the ~5K-cycle step). All previous fixes
//    (AGPR/LDS/named/barrier surgery) still presented invariant loads.
//  - Fix: TWO copies of the packed weights (2x196KB, L2-hot); the in-loop
//    base offset toggles each step through an asm-opaque update ->
//    loads are loop-VARIANT -> batched issue + vmcnt(N) pipelining
//    (the m97 GEMM pattern the compiler demonstrably emits).
//  - Everything else = R10 (best-known structure): 512thr/8 waves/16 nodes,
//    1 barrier/step, named acc/bias/state, folded W2 (k_tr2 eliminated),
//    per-node gbias, rcp sigmoid/tanh, mid-loop x prefetch.
// ---------------------------------------------------------------------------

#define T_DIM 336
#define N_DIM 3233
#define E_DIM 20000
#define FEAT  14
#define D_DIM 64
#define H_DIM 128
#define ET    (E_DIM + N_DIM)     // edges + self loops = 23233
#define WCOPY 98304               // f16 elements per weight copy (8*4*6*64*8)

typedef _Float16 f16;
typedef _Float16 half8_t __attribute__((ext_vector_type(8)));
typedef float float4_t __attribute__((ext_vector_type(4)));

__device__ __forceinline__ float sigf(float x) {
    return __builtin_amdgcn_rcpf(1.f + exp2f(-1.4426950408889634f * x));
}
__device__ __forceinline__ float tanhfast(float x) {
    return 1.f - 2.f * __builtin_amdgcn_rcpf(1.f + exp2f(2.8853900817779268f * x));
}

// ---------------- CSR build (deterministic) ----------------

__global__ void k_init(int* cnt, int* fill) {
    int i = blockIdx.x * 256 + threadIdx.x;
    if (i < N_DIM) { cnt[i] = 0; fill[i] = 0; }
}

__global__ void k_cnt(const int* __restrict__ ei, int* cnt) {
    int e = blockIdx.x * 256 + threadIdx.x;
    if (e < E_DIM) atomicAdd(&cnt[ei[E_DIM + e]], 1);
}

__global__ void k_scan(const int* __restrict__ cnt, int* __restrict__ rowp) {
    __shared__ int csum[1024];
    int tid = threadIdx.x;
    int base = tid * 4;
    int v[4];
    int s = 0;
    #pragma unroll
    for (int m = 0; m < 4; m++) {
        int idx = base + m;
        int len = (idx < N_DIM) ? (cnt[idx] + 1) : 0;
        v[m] = s; s += len;
    }
    csum[tid] = s;
    __syncthreads();
    for (int off = 1; off < 1024; off <<= 1) {
        int t2 = (tid >= off) ? csum[tid - off] : 0;
        __syncthreads();
        csum[tid] += t2;
        __syncthreads();
    }
    int pre = (tid > 0) ? csum[tid - 1] : 0;
    #pragma unroll
    for (int m = 0; m < 4; m++) {
        int idx = base + m;
        if (idx <= N_DIM) rowp[idx] = pre + v[m];
    }
}

__global__ void k_fill(const int* __restrict__ ei, const int* __restrict__ rowp,
                       int* fill, int* __restrict__ eid) {
    int e = blockIdx.x * 256 + threadIdx.x;
    if (e < ET) {
        int d = (e < E_DIM) ? ei[E_DIM + e] : (e - E_DIM);
        int p = rowp[d] + atomicAdd(&fill[d], 1);
        eid[p] = e;
    }
}

__global__ void k_sortdeg(const float* __restrict__ ew, const int* __restrict__ rowp,
                          int* __restrict__ eid, float* __restrict__ dis) {
    int n = blockIdx.x * 256 + threadIdx.x;
    if (n >= N_DIM) return;
    int p0 = rowp[n], p1 = rowp[n + 1];
    for (int i = p0 + 1; i < p1; i++) {
        int key = eid[i];
        int j = i - 1;
        while (j >= p0 && eid[j] > key) { eid[j + 1] = eid[j]; j--; }
        eid[j + 1] = key;
    }
    float deg = 0.f;
    for (int p = p0; p < p1; p++) {
        int e = eid[p];
        deg += (e < E_DIM) ? ew[e] : 1.0f;
    }
    dis[n] = rsqrtf(deg);
}

__global__ void k_csrmat(const int* __restrict__ ei, const float* __restrict__ ew,
                         const float* __restrict__ dis, const int* __restrict__ rowp,
                         const int* __restrict__ eid, int* __restrict__ csrc,
                         float* __restrict__ cnrm) {
    int n = blockIdx.x * 256 + threadIdx.x;
    if (n >= N_DIM) return;
    float dn = dis[n];
    int p0 = rowp[n], p1 = rowp[n + 1];
    for (int p = p0; p < p1; p++) {
        int e = eid[p];
        int s; float w;
        if (e < E_DIM) { s = ei[e]; w = ew[e]; }
        else           { s = e - E_DIM; w = 1.0f; }
        csrc[p] = s;
        cnrm[p] = dis[s] * w * dn;
    }
}

// ---------------- weight prep: fold W2 into Wih, pack B-fragments ----------------
// fragment idx = ((wv*4+ct)*6+ks)*64 + lane; gate g = 128ct+16wv+r.
// ks 0-1: W'[k][g] = sum_d W2[k][d]*Wih[g][d]   (k = 32ks+8q+j, ah-space)
// ks 2-5: Whh[g][k-64]                          (k-64 = 32(ks-2)+8q+j)
__global__ void k_wprep(const float* __restrict__ W2, const float* __restrict__ Wih,
                        const float* __restrict__ Whh, f16* __restrict__ wfbuf) {
    int idx = blockIdx.x * 256 + threadIdx.x;
    if (idx >= 8 * 4 * 6 * 64) return;
    int lane = idx & 63;
    int ks = (idx >> 6) % 6;
    int ct = ((idx >> 6) / 6) & 3;
    int wv = (idx >> 6) / 24;
    int q = lane >> 4, r = lane & 15;
    int g = 128 * ct + 16 * wv + r;
    f16* dst = wfbuf + (long)idx * 8;
    if (ks < 2) {
        const float* wir = Wih + (long)g * 64;
        #pragma unroll
        for (int j = 0; j < 8; j++) {
            int k = 32 * ks + 8 * q + j;
            const float* w2r = W2 + (long)k * 64;
            float s = 0.f;
            #pragma unroll 16
            for (int d = 0; d < 64; d++) s += w2r[d] * wir[d];
            dst[j] = (f16)s;
        }
    } else {
        const float* src = Whh + (long)g * 128 + 32 * (ks - 2) + 8 * q;
        #pragma unroll
        for (int j = 0; j < 8; j++) dst[j] = (f16)src[j];
    }
}

// duplicate the weight pack (ping-pong copy 1)
__global__ void k_dup(const f16* __restrict__ src, f16* __restrict__ dst) {
    int i = blockIdx.x * 256 + threadIdx.x;   // 12288 float4 chunks
    if (i < 12288) ((float4_t*)dst)[i] = ((const float4_t*)src)[i];
}

// gbias[n][g] = bih[g]+bhh[g] + sum_d (b2[d]+county[n][d])*Wih[g][d]
__global__ void k_gbias(const float* __restrict__ county, const float* __restrict__ b2,
                        const float* __restrict__ Wih, const float* __restrict__ bih,
                        const float* __restrict__ bhh, float* __restrict__ gbias) {
    long id = (long)blockIdx.x * 256 + threadIdx.x;
    if (id >= (long)N_DIM * 512) return;
    int n = (int)(id >> 9), g = (int)(id & 511);
    const float* wir = Wih + (long)g * 64;
    const float* cn = county + (long)n * 64;
    float s = bih[g] + bhh[g];
    #pragma unroll 16
    for (int d = 0; d < 64; d++) s += (b2[d] + cn[d]) * wir[d];
    gbias[id] = s;
}

// ---------------- GCN1a: aggX = A.x  (14-dim gather, 4 timesteps/wave) ----------------
__global__ void k_aggx(const float* __restrict__ x, const int* __restrict__ rowp,
                       const int* __restrict__ csrc, const float* __restrict__ cnrm,
                       float* __restrict__ aggX, int tc) {
    int lane = threadIdx.x & 63;
    long wid = ((long)blockIdx.x * 256 + threadIdx.x) >> 6;
    int ntg = (tc + 3) >> 2;
    if (wid >= (long)N_DIM * ntg) return;
    int n = (int)(wid % N_DIM);
    int tg = (int)(wid / N_DIM);
    int j = lane >> 4, d = lane & 15;
    int tj = 4 * tg + j;
    bool live = (d < FEAT) && (tj < tc);
    float acc = 0.f;
    int p0 = rowp[n], p1 = rowp[n + 1];
    for (int p = p0; p < p1; p++) {
        int s = csrc[p];
        float w = cnrm[p];
        if (live) acc += w * x[((long)tj * N_DIM + s) * FEAT + d];
    }
    if (tj < tc) aggX[((long)tj * N_DIM + n) * 16 + d] = acc;
}

// ---------------- GCN1b: h = relu(aggX.W1 + b1) -> f16 ----------------
__global__ void k_tr1(const float* __restrict__ aggX, const float* __restrict__ W1,
                      const float* __restrict__ b1, f16* __restrict__ h, long rows) {
    int lane = threadIdx.x & 63;
    long wid = ((long)blockIdx.x * 256 + threadIdx.x) >> 6;
    float wc[FEAT];
    #pragma unroll
    for (int k = 0; k < FEAT; k++) wc[k] = W1[k * 64 + lane];
    float bb = b1[lane];
    long r0 = wid * 2;
    if (r0 >= rows) return;
    long r1 = r0 + 1;
    bool has1 = (r1 < rows);
    const float* p0 = aggX + r0 * 16;
    const float* p1 = aggX + (has1 ? r1 : r0) * 16;
    float a0 = bb, a1 = bb;
    #pragma unroll
    for (int k = 0; k < FEAT; k++) { a0 += p0[k] * wc[k]; a1 += p1[k] * wc[k]; }
    h[r0 * 64 + lane] = (f16)fmaxf(a0, 0.f);
    if (has1) h[r1 * 64 + lane] = (f16)fmaxf(a1, 0.f);
}

// ---------------- GCN2a: ah = A.h  (f16 gather -> f16 out, 4 timesteps/wave) ----------------
__global__ void k_agg2(const f16* __restrict__ h, const int* __restrict__ rowp,
                       const int* __restrict__ csrc, const float* __restrict__ cnrm,
                       f16* __restrict__ ah, int tc) {
    int lane = threadIdx.x & 63;
    long wid = ((long)blockIdx.x * 256 + threadIdx.x) >> 6;
    int ntg = (tc + 3) >> 2;
    if (wid >= (long)N_DIM * ntg) return;
    int n = (int)(wid % N_DIM);
    int tg = (int)(wid / N_DIM);
    int tbase = 4 * tg;
    float acc0 = 0.f, acc1 = 0.f, acc2 = 0.f, acc3 = 0.f;
    int p0 = rowp[n], p1 = rowp[n + 1];
    for (int p = p0; p < p1; p++) {
        int s = csrc[p];
        float w = cnrm[p];
        const f16* base = h + ((long)tbase * N_DIM + s) * 64 + lane;
        acc0 += w * (float)base[0];
        if (tbase + 1 < tc) acc1 += w * (float)base[(long)N_DIM * 64];
        if (tbase + 2 < tc) acc2 += w * (float)base[(long)N_DIM * 128];
        if (tbase + 3 < tc) acc3 += w * (float)base[(long)N_DIM * 192];
    }
    f16* dst = ah + ((long)tbase * N_DIM + n) * 64 + lane;
    dst[0] = (f16)acc0;
    if (tbase + 1 < tc) dst[(long)N_DIM * 64] = (f16)acc1;
    if (tbase + 2 < tc) dst[(long)N_DIM * 128] = (f16)acc2;
    if (tbase + 3 < tc) dst[(long)N_DIM * 192] = (f16)acc3;
}

// ---------------- LSTM chunk: ping-pong streamed weights, 1 barrier/step ----------------
// Wave wv owns gate-types ct={i,f,g,o} x units [16wv,16wv+16). Thread (wv,q,r):
// nodes 4q+reg, unit u=16wv+r -> all 4 gates of (node,u) live in acc{ct}[reg].
// Weight loads are IN-LOOP and loop-VARIANT (base toggles through an opaque
// asm update) -> no LICM, fresh per-iteration landing regs, batched issue.

#define LOADW(ct, ks) const half8_t w_##ct##_##ks = \
    *(const half8_t*)(wfbuf + woff + (long)(((((wv * 4 + ct) * 6 + ks) << 6) + lane) * 8))

#define MFMA(acc, a_, w_) acc = __builtin_amdgcn_mfma_f32_16x16x32_f16(a_, w_, acc, 0, 0, 0)

#define ELEM(reg) { \
    float gi = acc0[reg], gf = acc1[reg], gg = acc2[reg], go = acc3[reg]; \
    float c = sigf(gf) * cv4[reg] + sigf(gi) * tanhfast(gg); \
    float hh = sigf(go) * tanhfast(c); \
    cv4[reg] = c; hv4[reg] = hh; \
    xh[buf ^ 1][4 * q + reg][u] = (f16)hh; }

__global__ __launch_bounds__(512, 1) void k_lstm(
    const f16* __restrict__ ah, const f16* __restrict__ wfbuf,
    const float* __restrict__ gbias,
    const float* __restrict__ Wm1, const float* __restrict__ bm1,
    const float* __restrict__ Wm2, const float* __restrict__ bm2,
    float* __restrict__ Hst, float* __restrict__ Cst,
    int tc, int do_init, int do_head, float* __restrict__ out) {
    __shared__ __align__(16) f16   xh[2][16][136];   // h units, double-buffered
    __shared__ __align__(16) float hd[16][132];
    __shared__ __align__(16) float zs[16][64];

    int tid = threadIdx.x;
    int wv = tid >> 6, lane = tid & 63, q = lane >> 4, r = lane & 15;
    int nb = blockIdx.x * 16;
    int cnt = min(16, N_DIM - nb);
    int u = 16 * wv + r;

    // per-node folded bias: 4 named float4 (small; ok if compiler respills)
    int gn0 = nb + 4 * q;     if (gn0 >= N_DIM) gn0 = N_DIM - 1;
    int gn1 = nb + 4 * q + 1; if (gn1 >= N_DIM) gn1 = N_DIM - 1;
    int gn2 = nb + 4 * q + 2; if (gn2 >= N_DIM) gn2 = N_DIM - 1;
    int gn3 = nb + 4 * q + 3; if (gn3 >= N_DIM) gn3 = N_DIM - 1;
    float4_t gb0, gb1, gb2, gb3;
    gb0[0] = gbias[(long)gn0 * 512 + 0 * 128 + u];
    gb0[1] = gbias[(long)gn1 * 512 + 0 * 128 + u];
    gb0[2] = gbias[(long)gn2 * 512 + 0 * 128 + u];
    gb0[3] = gbias[(long)gn3 * 512 + 0 * 128 + u];
    gb1[0] = gbias[(long)gn0 * 512 + 1 * 128 + u];
    gb1[1] = gbias[(long)gn1 * 512 + 1 * 128 + u];
    gb1[2] = gbias[(long)gn2 * 512 + 1 * 128 + u];
    gb1[3] = gbias[(long)gn3 * 512 + 1 * 128 + u];
    gb2[0] = gbias[(long)gn0 * 512 + 2 * 128 + u];
    gb2[1] = gbias[(long)gn1 * 512 + 2 * 128 + u];
    gb2[2] = gbias[(long)gn2 * 512 + 2 * 128 + u];
    gb2[3] = gbias[(long)gn3 * 512 + 2 * 128 + u];
    gb3[0] = gbias[(long)gn0 * 512 + 3 * 128 + u];
    gb3[1] = gbias[(long)gn1 * 512 + 3 * 128 + u];
    gb3[2] = gbias[(long)gn2 * 512 + 3 * 128 + u];
    gb3[3] = gbias[(long)gn3 * 512 + 3 * 128 + u];

    // state: named float4 vectors
    float4_t cv4, hv4;
    {
        int node = 4 * q;
        bool lv0 = (!do_init) && (node < cnt);
        bool lv1 = (!do_init) && (node + 1 < cnt);
        bool lv2 = (!do_init) && (node + 2 < cnt);
        bool lv3 = (!do_init) && (node + 3 < cnt);
        hv4[0] = lv0 ? Hst[(long)(nb + node) * H_DIM + u] : 0.f;
        hv4[1] = lv1 ? Hst[(long)(nb + node + 1) * H_DIM + u] : 0.f;
        hv4[2] = lv2 ? Hst[(long)(nb + node + 2) * H_DIM + u] : 0.f;
        hv4[3] = lv3 ? Hst[(long)(nb + node + 3) * H_DIM + u] : 0.f;
        cv4[0] = lv0 ? Cst[(long)(nb + node) * H_DIM + u] : 0.f;
        cv4[1] = lv1 ? Cst[(long)(nb + node + 1) * H_DIM + u] : 0.f;
        cv4[2] = lv2 ? Cst[(long)(nb + node + 2) * H_DIM + u] : 0.f;
        cv4[3] = lv3 ? Cst[(long)(nb + node + 3) * H_DIM + u] : 0.f;
        xh[0][node][u]     = (f16)hv4[0];
        xh[0][node + 1][u] = (f16)hv4[1];
        xh[0][node + 2][u] = (f16)hv4[2];
        xh[0][node + 3][u] = (f16)hv4[3];
    }

    int xrow = nb + r; if (xrow >= N_DIM) xrow = N_DIM - 1;
    half8_t xa = *(const half8_t*)(ah + (long)xrow * 64 + 8 * q);
    half8_t xb = *(const half8_t*)(ah + (long)xrow * 64 + 32 + 8 * q);

    int buf = 0;
    unsigned woff = 0;   // ping-pong offset: toggles 0 <-> WCOPY, opaque to LICM
    __syncthreads();

    for (int t = 0; t < tc; t++) {
        // ---- in-loop weight stream (loop-variant: woff is opaque) ----
        LOADW(0, 0); LOADW(1, 0); LOADW(2, 0); LOADW(3, 0);
        LOADW(0, 1); LOADW(1, 1); LOADW(2, 1); LOADW(3, 1);
        LOADW(0, 2); LOADW(1, 2); LOADW(2, 2); LOADW(3, 2);
        LOADW(0, 3); LOADW(1, 3); LOADW(2, 3); LOADW(3, 3);
        LOADW(0, 4); LOADW(1, 4); LOADW(2, 4); LOADW(3, 4);
        LOADW(0, 5); LOADW(1, 5); LOADW(2, 5); LOADW(3, 5);

        half8_t a2 = *(const half8_t*)&xh[buf][r][8 * q];
        half8_t a3 = *(const half8_t*)&xh[buf][r][32 + 8 * q];
        half8_t a4 = *(const half8_t*)&xh[buf][r][64 + 8 * q];
        half8_t a5 = *(const half8_t*)&xh[buf][r][96 + 8 * q];

        float4_t acc0 = gb0, acc1 = gb1, acc2 = gb2, acc3 = gb3;

        MFMA(acc0, xa, w_0_0); MFMA(acc1, xa, w_1_0); MFMA(acc2, xa, w_2_0); MFMA(acc3, xa, w_3_0);
        MFMA(acc0, xb, w_0_1); MFMA(acc1, xb, w_1_1); MFMA(acc2, xb, w_2_1); MFMA(acc3, xb, w_3_1);

        // prefetch next x -- xa/xb dead; latency hides under h-part MFMAs
        int tn = (t + 1 < tc) ? t + 1 : t;
        const f16* xp = ah + ((long)tn * N_DIM + xrow) * 64;
        xa = *(const half8_t*)(xp + 8 * q);
        xb = *(const half8_t*)(xp + 32 + 8 * q);

        MFMA(acc0, a2, w_0_2); MFMA(acc1, a2, w_1_2); MFMA(acc2, a2, w_2_2); MFMA(acc3, a2, w_3_2);
        MFMA(acc0, a3, w_0_3); MFMA(acc1, a3, w_1_3); MFMA(acc2, a3, w_2_3); MFMA(acc3, a3, w_3_3);
        MFMA(acc0, a4, w_0_4); MFMA(acc1, a4, w_1_4); MFMA(acc2, a4, w_2_4); MFMA(acc3, a4, w_3_4);
        MFMA(acc0, a5, w_0_5); MFMA(acc1, a5, w_1_5); MFMA(acc2, a5, w_2_5); MFMA(acc3, a5, w_3_5);

        ELEM(0) ELEM(1) ELEM(2) ELEM(3)

        __syncthreads();
        buf ^= 1;
        woff ^= WCOPY;
        asm volatile("" : "+s"(woff));   // opaque: defeat LICM/unroll analysis
    }

    {
        int node = 4 * q;
        if (node < cnt)     { Hst[(long)(nb + node) * H_DIM + u] = hv4[0];
                              Cst[(long)(nb + node) * H_DIM + u] = cv4[0]; }
        if (node + 1 < cnt) { Hst[(long)(nb + node + 1) * H_DIM + u] = hv4[1];
                              Cst[(long)(nb + node + 1) * H_DIM + u] = cv4[1]; }
        if (node + 2 < cnt) { Hst[(long)(nb + node + 2) * H_DIM + u] = hv4[2];
                              Cst[(long)(nb + node + 2) * H_DIM + u] = cv4[2]; }
        if (node + 3 < cnt) { Hst[(long)(nb + node + 3) * H_DIM + u] = hv4[3];
                              Cst[(long)(nb + node + 3) * H_DIM + u] = cv4[3]; }
    }
    if (!do_head) return;

    hd[4 * q + 0][u] = hv4[0];
    hd[4 * q + 1][u] = hv4[1];
    hd[4 * q + 2][u] = hv4[2];
    hd[4 * q + 3][u] = hv4[3];
    __syncthreads();

    for (int i = tid; i < 16 * 64; i += 512) {
        int n = i >> 6, m = i & 63;
        float a = bm1[m];
        #pragma unroll 8
        for (int k = 0; k < H_DIM; k++) a += hd[n][k] * Wm1[k * 64 + m];
        zs[n][m] = fmaxf(a, 0.f);
    }
    __syncthreads();
    if (tid < cnt) {
        float a = bm2[0];
        #pragma unroll 8
        for (int m = 0; m < 64; m++) a += zs[tid][m] * Wm2[m];
        out[nb + tid] = a;
    }
}

// ---------------------------------------------------------------------------

extern "C" void kernel_launch(void* const* d_in, const int* in_sizes, int n_in,
                              void* d_out, int out_size, void* d_ws, size_t ws_size,
                              hipStream_t stream) {
    const float* x   = (const float*)d_in[0];
    const int*   ei  = (const int*)d_in[1];
    const float* ew  = (const float*)d_in[2];
    const float* W1  = (const float*)d_in[3];
    const float* b1  = (const float*)d_in[4];
    const float* W2  = (const float*)d_in[5];
    const float* b2  = (const float*)d_in[6];
    const float* cb  = (const float*)d_in[7];
    const float* Wih = (const float*)d_in[8];
    const float* Whh = (const float*)d_in[9];
    const float* bih = (const float*)d_in[10];
    const float* bhh = (const float*)d_in[11];
    const float* Wm1 = (const float*)d_in[12];
    const float* bm1 = (const float*)d_in[13];
    const float* Wm2 = (const float*)d_in[14];
    const float* bm2 = (const float*)d_in[15];
    float* out = (float*)d_out;
    (void)in_sizes; (void)n_in; (void)out_size;

    char* ws = (char*)d_ws;
    size_t off = 0;
    auto alloc = [&](size_t bytes) -> char* {
        char* p = ws + off;
        off = (off + bytes + 255) & ~(size_t)255;
        return p;
    };
    float* dis   = (float*)alloc(N_DIM * 4);
    int*   cnt   = (int*)alloc(N_DIM * 4);
    int*   fill  = (int*)alloc(N_DIM * 4);
    int*   rowp  = (int*)alloc((N_DIM + 1) * 4);
    int*   eid   = (int*)alloc(ET * 4);
    int*   csrc  = (int*)alloc(ET * 4);
    float* cnrm  = (float*)alloc(ET * 4);
    float* Hst   = (float*)alloc((size_t)N_DIM * H_DIM * 4);
    float* Cst   = (float*)alloc((size_t)N_DIM * H_DIM * 4);
    f16*   wfbuf = (f16*)alloc((size_t)2 * WCOPY * 2);   // TWO copies (ping-pong)
    float* gbias = (float*)alloc((size_t)N_DIM * 512 * 4);

    // largest Tc dividing 336 whose chunk buffers (rows*320B) fit
    const int cand[] = {336, 168, 112, 84, 56, 48, 28, 16, 8, 4};
    int Tc = 4;
    for (int i = 0; i < 10; i++) {
        size_t need = off + (size_t)cand[i] * N_DIM * 320 + 4096;
        if (need <= ws_size) { Tc = cand[i]; break; }
    }
    long rows = (long)Tc * N_DIM;
    float* aggX  = (float*)alloc(rows * 64);    // [rows][16] fp32 (14 used)
    f16*   hbuf  = (f16*)alloc(rows * 128);     // h f16
    f16*   ahbuf = (f16*)alloc(rows * 128);     // ah f16

    // --- one-time: CSR build + weight fold/pack (x2) + per-node gate bias ---
    k_init<<<(N_DIM + 255) / 256, 256, 0, stream>>>(cnt, fill);
    k_cnt<<<(E_DIM + 255) / 256, 256, 0, stream>>>(ei, cnt);
    k_scan<<<1, 1024, 0, stream>>>(cnt, rowp);
    k_fill<<<(ET + 255) / 256, 256, 0, stream>>>(ei, rowp, fill, eid);
    k_sortdeg<<<(N_DIM + 255) / 256, 256, 0, stream>>>(ew, rowp, eid, dis);
    k_csrmat<<<(N_DIM + 255) / 256, 256, 0, stream>>>(ei, ew, dis, rowp, eid, csrc, cnrm);
    k_wprep<<<48, 256, 0, stream>>>(W2, Wih, Whh, wfbuf);
    k_dup<<<48, 256, 0, stream>>>(wfbuf, wfbuf + WCOPY);
    k_gbias<<<(int)(((long)N_DIM * 512 + 255) / 256), 256, 0, stream>>>(cb, b2, Wih, bih, bhh, gbias);

    int ntg = (Tc + 3) >> 2;
    long aggWaves = (long)N_DIM * ntg;
    int aggBlocks = (int)((aggWaves + 3) / 4);
    int trBlocks  = (int)(((rows + 1) / 2 + 3) / 4);
    int lblocks   = (N_DIM + 15) / 16;
    int nChunks   = T_DIM / Tc;

    for (int c = 0; c < nChunks; c++) {
        long t0 = (long)c * Tc;
        k_aggx<<<aggBlocks, 256, 0, stream>>>(x + t0 * N_DIM * FEAT, rowp, csrc, cnrm, aggX, Tc);
        k_tr1<<<trBlocks, 256, 0, stream>>>(aggX, W1, b1, hbuf, rows);
        k_agg2<<<aggBlocks, 256, 0, stream>>>(hbuf, rowp, csrc, cnrm, ahbuf, Tc);
        k_lstm<<<lblocks, 512, 0, stream>>>(ahbuf, wfbuf, gbias, Wm1, bm1, Wm2, bm2,
                                            Hst, Cst, Tc, c == 0 ? 1 : 0,
                                            c == nChunks - 1 ? 1 : 0, out);
    }
}

// Round 13
// 1161.162 us; speedup vs baseline: 1.4432x; 1.4432x over previous
//
#include <hip/hip_runtime.h>
#include <math.h>

// ---------------------------------------------------------------------------
// SpatioTemporalOutageModel:
//   GCN(14->64) -> GCN(64->64)+county_bias -> LSTM(64->128, T=336) -> MLP(128->64->1)
//
// R13 (consolidation):
//  - LSTM: exact R6 revert (best measured: 221us, VGPR=92). R6-R12 established
//    the ~2.6us/step cost is INVARIANT to weight residency (L2/AGPR/LDS/named/
//    ping-pong) and barrier semantics -- compiler serializes the per-step load
//    set from a small register budget; no source trick changed it.
//  - GCN1 fused: k_aggx + k_tr1 -> k_gcn1 (gather 14-dim to 1KB LDS tile,
//    transform in-kernel). Kills the 87MB fp32 aggX round-trip + launches.
//  - Chunk footprint 320->256 B/row -> Tc up to 336 (fewer chunks/launches).
// ---------------------------------------------------------------------------

#define T_DIM 336
#define N_DIM 3233
#define E_DIM 20000
#define FEAT  14
#define D_DIM 64
#define H_DIM 128
#define ET    (E_DIM + N_DIM)     // edges + self loops = 23233

typedef _Float16 f16;
typedef _Float16 half8_t __attribute__((ext_vector_type(8)));
typedef float float4_t __attribute__((ext_vector_type(4)));

__device__ __forceinline__ float sigf(float x) {
    return __builtin_amdgcn_rcpf(1.f + exp2f(-1.4426950408889634f * x));
}
__device__ __forceinline__ float tanhfast(float x) {
    return 1.f - 2.f * __builtin_amdgcn_rcpf(1.f + exp2f(2.8853900817779268f * x));
}

// ---------------- CSR build (deterministic) ----------------

__global__ void k_init(int* cnt, int* fill) {
    int i = blockIdx.x * 256 + threadIdx.x;
    if (i < N_DIM) { cnt[i] = 0; fill[i] = 0; }
}

__global__ void k_cnt(const int* __restrict__ ei, int* cnt) {
    int e = blockIdx.x * 256 + threadIdx.x;
    if (e < E_DIM) atomicAdd(&cnt[ei[E_DIM + e]], 1);
}

__global__ void k_scan(const int* __restrict__ cnt, int* __restrict__ rowp) {
    __shared__ int csum[1024];
    int tid = threadIdx.x;
    int base = tid * 4;
    int v[4];
    int s = 0;
    #pragma unroll
    for (int m = 0; m < 4; m++) {
        int idx = base + m;
        int len = (idx < N_DIM) ? (cnt[idx] + 1) : 0;
        v[m] = s; s += len;
    }
    csum[tid] = s;
    __syncthreads();
    for (int off = 1; off < 1024; off <<= 1) {
        int t2 = (tid >= off) ? csum[tid - off] : 0;
        __syncthreads();
        csum[tid] += t2;
        __syncthreads();
    }
    int pre = (tid > 0) ? csum[tid - 1] : 0;
    #pragma unroll
    for (int m = 0; m < 4; m++) {
        int idx = base + m;
        if (idx <= N_DIM) rowp[idx] = pre + v[m];
    }
}

__global__ void k_fill(const int* __restrict__ ei, const int* __restrict__ rowp,
                       int* fill, int* __restrict__ eid) {
    int e = blockIdx.x * 256 + threadIdx.x;
    if (e < ET) {
        int d = (e < E_DIM) ? ei[E_DIM + e] : (e - E_DIM);
        int p = rowp[d] + atomicAdd(&fill[d], 1);
        eid[p] = e;
    }
}

__global__ void k_sortdeg(const float* __restrict__ ew, const int* __restrict__ rowp,
                          int* __restrict__ eid, float* __restrict__ dis) {
    int n = blockIdx.x * 256 + threadIdx.x;
    if (n >= N_DIM) return;
    int p0 = rowp[n], p1 = rowp[n + 1];
    for (int i = p0 + 1; i < p1; i++) {
        int key = eid[i];
        int j = i - 1;
        while (j >= p0 && eid[j] > key) { eid[j + 1] = eid[j]; j--; }
        eid[j + 1] = key;
    }
    float deg = 0.f;
    for (int p = p0; p < p1; p++) {
        int e = eid[p];
        deg += (e < E_DIM) ? ew[e] : 1.0f;
    }
    dis[n] = rsqrtf(deg);
}

__global__ void k_csrmat(const int* __restrict__ ei, const float* __restrict__ ew,
                         const float* __restrict__ dis, const int* __restrict__ rowp,
                         const int* __restrict__ eid, int* __restrict__ csrc,
                         float* __restrict__ cnrm) {
    int n = blockIdx.x * 256 + threadIdx.x;
    if (n >= N_DIM) return;
    float dn = dis[n];
    int p0 = rowp[n], p1 = rowp[n + 1];
    for (int p = p0; p < p1; p++) {
        int e = eid[p];
        int s; float w;
        if (e < E_DIM) { s = ei[e]; w = ew[e]; }
        else           { s = e - E_DIM; w = 1.0f; }
        csrc[p] = s;
        cnrm[p] = dis[s] * w * dn;
    }
}

// ---------------- weight prep: fold W2 into Wih, pack B-fragments ----------------
// fragment idx = ((wv*4+ct)*6+ks)*64 + lane; gate g = 128ct+16wv+r.
// ks 0-1: W'[k][g] = sum_d W2[k][d]*Wih[g][d]   (k = 32ks+8q+j, ah-space)
// ks 2-5: Whh[g][k-64]                          (k-64 = 32(ks-2)+8q+j)
__global__ void k_wprep(const float* __restrict__ W2, const float* __restrict__ Wih,
                        const float* __restrict__ Whh, f16* __restrict__ wfbuf) {
    int idx = blockIdx.x * 256 + threadIdx.x;
    if (idx >= 8 * 4 * 6 * 64) return;
    int lane = idx & 63;
    int ks = (idx >> 6) % 6;
    int ct = ((idx >> 6) / 6) & 3;
    int wv = (idx >> 6) / 24;
    int q = lane >> 4, r = lane & 15;
    int g = 128 * ct + 16 * wv + r;
    f16* dst = wfbuf + (long)idx * 8;
    if (ks < 2) {
        const float* wir = Wih + (long)g * 64;
        #pragma unroll
        for (int j = 0; j < 8; j++) {
            int k = 32 * ks + 8 * q + j;
            const float* w2r = W2 + (long)k * 64;
            float s = 0.f;
            #pragma unroll 16
            for (int d = 0; d < 64; d++) s += w2r[d] * wir[d];
            dst[j] = (f16)s;
        }
    } else {
        const float* src = Whh + (long)g * 128 + 32 * (ks - 2) + 8 * q;
        #pragma unroll
        for (int j = 0; j < 8; j++) dst[j] = (f16)src[j];
    }
}

// gbias[n][g] = bih[g]+bhh[g] + sum_d (b2[d]+county[n][d])*Wih[g][d]
__global__ void k_gbias(const float* __restrict__ county, const float* __restrict__ b2,
                        const float* __restrict__ Wih, const float* __restrict__ bih,
                        const float* __restrict__ bhh, float* __restrict__ gbias) {
    long id = (long)blockIdx.x * 256 + threadIdx.x;
    if (id >= (long)N_DIM * 512) return;
    int n = (int)(id >> 9), g = (int)(id & 511);
    const float* wir = Wih + (long)g * 64;
    const float* cn = county + (long)n * 64;
    float s = bih[g] + bhh[g];
    #pragma unroll 16
    for (int d = 0; d < 64; d++) s += (b2[d] + cn[d]) * wir[d];
    gbias[id] = s;
}

// ---------------- GCN1 fused: h = relu((A.x)@W1 + b1) -> f16 ----------------
// One wave per (n, 4 timesteps). Phase 1: 14-dim gather (lane = (tslot, d)).
// Phase 2: stage [4t][16d] in LDS, transform to 64 cols (lane = col).
__global__ void k_gcn1(const float* __restrict__ x, const int* __restrict__ rowp,
                       const int* __restrict__ csrc, const float* __restrict__ cnrm,
                       const float* __restrict__ W1, const float* __restrict__ b1,
                       f16* __restrict__ h, int tc) {
    __shared__ float g1[4][4][16];   // [wave][tslot][dim]
    int lane = threadIdx.x & 63;
    int wv = threadIdx.x >> 6;
    long wid = ((long)blockIdx.x * 256 + threadIdx.x) >> 6;
    int ntg = (tc + 3) >> 2;
    bool wlive = wid < (long)N_DIM * ntg;

    int n = 0, tg = 0;
    if (wlive) { n = (int)(wid % N_DIM); tg = (int)(wid / N_DIM); }
    int j = lane >> 4, d = lane & 15;
    int tj = 4 * tg + j;
    bool live = wlive && (d < FEAT) && (tj < tc);

    float acc = 0.f;
    if (wlive) {
        int p0 = rowp[n], p1 = rowp[n + 1];
        for (int p = p0; p < p1; p++) {
            int s = csrc[p];
            float w = cnrm[p];
            if (live) acc += w * x[((long)tj * N_DIM + s) * FEAT + d];
        }
    }
    g1[wv][j][d] = acc;
    __syncthreads();

    if (!wlive) return;
    // transform: lane = output column; 4 t-slots each
    float wc[FEAT];
    #pragma unroll
    for (int k = 0; k < FEAT; k++) wc[k] = W1[k * 64 + lane];
    float bb = b1[lane];
    #pragma unroll
    for (int jj = 0; jj < 4; jj++) {
        int tjj = 4 * tg + jj;
        if (tjj >= tc) break;
        float a = bb;
        #pragma unroll
        for (int k = 0; k < FEAT; k++) a += g1[wv][jj][k] * wc[k];
        h[((long)tjj * N_DIM + n) * 64 + lane] = (f16)fmaxf(a, 0.f);
    }
}

// ---------------- GCN2a: ah = A.h  (f16 gather -> f16 out, 4 timesteps/wave) ----------------
__global__ void k_agg2(const f16* __restrict__ h, const int* __restrict__ rowp,
                       const int* __restrict__ csrc, const float* __restrict__ cnrm,
                       f16* __restrict__ ah, int tc) {
    int lane = threadIdx.x & 63;
    long wid = ((long)blockIdx.x * 256 + threadIdx.x) >> 6;
    int ntg = (tc + 3) >> 2;
    if (wid >= (long)N_DIM * ntg) return;
    int n = (int)(wid % N_DIM);
    int tg = (int)(wid / N_DIM);
    int tbase = 4 * tg;
    float acc0 = 0.f, acc1 = 0.f, acc2 = 0.f, acc3 = 0.f;
    int p0 = rowp[n], p1 = rowp[n + 1];
    for (int p = p0; p < p1; p++) {
        int s = csrc[p];
        float w = cnrm[p];
        const f16* base = h + ((long)tbase * N_DIM + s) * 64 + lane;
        acc0 += w * (float)base[0];
        if (tbase + 1 < tc) acc1 += w * (float)base[(long)N_DIM * 64];
        if (tbase + 2 < tc) acc2 += w * (float)base[(long)N_DIM * 128];
        if (tbase + 3 < tc) acc3 += w * (float)base[(long)N_DIM * 192];
    }
    f16* dst = ah + ((long)tbase * N_DIM + n) * 64 + lane;
    dst[0] = (f16)acc0;
    if (tbase + 1 < tc) dst[(long)N_DIM * 64] = (f16)acc1;
    if (tbase + 2 < tc) dst[(long)N_DIM * 128] = (f16)acc2;
    if (tbase + 3 < tc) dst[(long)N_DIM * 192] = (f16)acc3;
}

// ---------------- LSTM chunk (exact R6: f16 MFMA, pinned frags) + MLP head --------
// Wave wv owns gate-types ct={i,f,g,o} x units [16wv,16wv+16). Thread (wv,q,r):
// nodes 4q+reg, unit u=16wv+r -> all 4 gates of (node,u) live in acc[ct][reg].
__global__ __attribute__((amdgpu_flat_work_group_size(512, 512), amdgpu_waves_per_eu(2, 2)))
void k_lstm(
    const f16* __restrict__ ah, const f16* __restrict__ wfbuf,
    const float* __restrict__ gbias,
    const float* __restrict__ Wm1, const float* __restrict__ bm1,
    const float* __restrict__ Wm2, const float* __restrict__ bm2,
    float* __restrict__ Hst, float* __restrict__ Cst,
    int tc, int do_init, int do_head, float* __restrict__ out) {
    __shared__ __align__(16) f16   xh[2][16][136];   // h, double-buffered
    __shared__ __align__(16) float hd[16][132];      // head scratch
    __shared__ __align__(16) float zs[16][64];

    int tid = threadIdx.x;
    int wv = tid >> 6, lane = tid & 63, q = lane >> 4, r = lane & 15;
    int nb = blockIdx.x * 16;
    int cnt = min(16, N_DIM - nb);
    int u = 16 * wv + r;

    // weight fragments, pinned as asm outputs (R6 configuration)
    float4_t wfr[4][6];
    #pragma unroll
    for (int ct = 0; ct < 4; ct++)
        #pragma unroll
        for (int ks = 0; ks < 6; ks++)
            wfr[ct][ks] = *(const float4_t*)&wfbuf[(long)((((wv * 4 + ct) * 6 + ks) << 6) + lane) * 8];
    #pragma unroll
    for (int ct = 0; ct < 4; ct++)
        #pragma unroll
        for (int ks = 0; ks < 6; ks++)
            asm volatile("" : "+v"(wfr[ct][ks]));

    // per-node folded bias -- pinned
    float gb[4][4];
    #pragma unroll
    for (int reg = 0; reg < 4; reg++) {
        int node = 4 * q + reg;
        int gn = nb + node; if (gn >= N_DIM) gn = N_DIM - 1;
        #pragma unroll
        for (int ct = 0; ct < 4; ct++)
            gb[ct][reg] = gbias[(long)gn * 512 + 128 * ct + u];
    }
    #pragma unroll
    for (int ct = 0; ct < 4; ct++)
        #pragma unroll
        for (int reg = 0; reg < 4; reg++)
            asm volatile("" : "+v"(gb[ct][reg]));

    // state in VGPRs
    float cv[4], hvv[4];
    #pragma unroll
    for (int reg = 0; reg < 4; reg++) {
        int node = 4 * q + reg;
        bool live = (!do_init) && (node < cnt);
        hvv[reg] = live ? Hst[(long)(nb + node) * H_DIM + u] : 0.f;
        cv[reg]  = live ? Cst[(long)(nb + node) * H_DIM + u] : 0.f;
        xh[0][node][u] = (f16)hvv[reg];
    }

    int xrow = nb + r; if (xrow >= N_DIM) xrow = N_DIM - 1;
    half8_t xa = *(const half8_t*)(ah + (long)xrow * 64 + 8 * q);
    half8_t xb = *(const half8_t*)(ah + (long)xrow * 64 + 32 + 8 * q);

    int buf = 0;
    __syncthreads();

    for (int t = 0; t < tc; t++) {
        half8_t a2 = *(const half8_t*)&xh[buf][r][8 * q];
        half8_t a3 = *(const half8_t*)&xh[buf][r][32 + 8 * q];
        half8_t a4 = *(const half8_t*)&xh[buf][r][64 + 8 * q];
        half8_t a5 = *(const half8_t*)&xh[buf][r][96 + 8 * q];

        float4_t acc[4];
        #pragma unroll
        for (int ct = 0; ct < 4; ct++) {
            acc[ct][0] = gb[ct][0]; acc[ct][1] = gb[ct][1];
            acc[ct][2] = gb[ct][2]; acc[ct][3] = gb[ct][3];
        }
        #pragma unroll
        for (int ct = 0; ct < 4; ct++)
            acc[ct] = __builtin_amdgcn_mfma_f32_16x16x32_f16(xa, __builtin_bit_cast(half8_t, wfr[ct][0]), acc[ct], 0, 0, 0);
        #pragma unroll
        for (int ct = 0; ct < 4; ct++)
            acc[ct] = __builtin_amdgcn_mfma_f32_16x16x32_f16(xb, __builtin_bit_cast(half8_t, wfr[ct][1]), acc[ct], 0, 0, 0);

        // prefetch next x now -- xa/xb dead; latency hidden under groups 2-5
        int tn = (t + 1 < tc) ? t + 1 : t;
        const f16* xp = ah + ((long)tn * N_DIM + xrow) * 64;
        xa = *(const half8_t*)(xp + 8 * q);
        xb = *(const half8_t*)(xp + 32 + 8 * q);

        #pragma unroll
        for (int ct = 0; ct < 4; ct++)
            acc[ct] = __builtin_amdgcn_mfma_f32_16x16x32_f16(a2, __builtin_bit_cast(half8_t, wfr[ct][2]), acc[ct], 0, 0, 0);
        #pragma unroll
        for (int ct = 0; ct < 4; ct++)
            acc[ct] = __builtin_amdgcn_mfma_f32_16x16x32_f16(a3, __builtin_bit_cast(half8_t, wfr[ct][3]), acc[ct], 0, 0, 0);
        #pragma unroll
        for (int ct = 0; ct < 4; ct++)
            acc[ct] = __builtin_amdgcn_mfma_f32_16x16x32_f16(a4, __builtin_bit_cast(half8_t, wfr[ct][4]), acc[ct], 0, 0, 0);
        #pragma unroll
        for (int ct = 0; ct < 4; ct++)
            acc[ct] = __builtin_amdgcn_mfma_f32_16x16x32_f16(a5, __builtin_bit_cast(half8_t, wfr[ct][5]), acc[ct], 0, 0, 0);

        // elementwise in-register
        #pragma unroll
        for (int reg = 0; reg < 4; reg++) {
            float gi = acc[0][reg], gf = acc[1][reg], gg = acc[2][reg], go = acc[3][reg];
            float c = sigf(gf) * cv[reg] + sigf(gi) * tanhfast(gg);
            float hh = sigf(go) * tanhfast(c);
            cv[reg] = c; hvv[reg] = hh;
            xh[buf ^ 1][4 * q + reg][u] = (f16)hh;
        }
        __syncthreads();
        buf ^= 1;
    }

    #pragma unroll
    for (int reg = 0; reg < 4; reg++) {
        int node = 4 * q + reg;
        if (node < cnt) {
            Hst[(long)(nb + node) * H_DIM + u] = hvv[reg];
            Cst[(long)(nb + node) * H_DIM + u] = cv[reg];
        }
    }
    if (!do_head) return;

    #pragma unroll
    for (int reg = 0; reg < 4; reg++) hd[4 * q + reg][u] = hvv[reg];
    __syncthreads();

    for (int i = tid; i < 16 * 64; i += 512) {
        int n = i >> 6, m = i & 63;
        float a = bm1[m];
        #pragma unroll 8
        for (int k = 0; k < H_DIM; k++) a += hd[n][k] * Wm1[k * 64 + m];
        zs[n][m] = fmaxf(a, 0.f);
    }
    __syncthreads();
    if (tid < cnt) {
        float a = bm2[0];
        #pragma unroll 8
        for (int m = 0; m < 64; m++) a += zs[tid][m] * Wm2[m];
        out[nb + tid] = a;
    }
}

// ---------------------------------------------------------------------------

extern "C" void kernel_launch(void* const* d_in, const int* in_sizes, int n_in,
                              void* d_out, int out_size, void* d_ws, size_t ws_size,
                              hipStream_t stream) {
    const float* x   = (const float*)d_in[0];
    const int*   ei  = (const int*)d_in[1];
    const float* ew  = (const float*)d_in[2];
    const float* W1  = (const float*)d_in[3];
    const float* b1  = (const float*)d_in[4];
    const float* W2  = (const float*)d_in[5];
    const float* b2  = (const float*)d_in[6];
    const float* cb  = (const float*)d_in[7];
    const float* Wih = (const float*)d_in[8];
    const float* Whh = (const float*)d_in[9];
    const float* bih = (const float*)d_in[10];
    const float* bhh = (const float*)d_in[11];
    const float* Wm1 = (const float*)d_in[12];
    const float* bm1 = (const float*)d_in[13];
    const float* Wm2 = (const float*)d_in[14];
    const float* bm2 = (const float*)d_in[15];
    float* out = (float*)d_out;
    (void)in_sizes; (void)n_in; (void)out_size;

    char* ws = (char*)d_ws;
    size_t off = 0;
    auto alloc = [&](size_t bytes) -> char* {
        char* p = ws + off;
        off = (off + bytes + 255) & ~(size_t)255;
        return p;
    };
    float* dis   = (float*)alloc(N_DIM * 4);
    int*   cnt   = (int*)alloc(N_DIM * 4);
    int*   fill  = (int*)alloc(N_DIM * 4);
    int*   rowp  = (int*)alloc((N_DIM + 1) * 4);
    int*   eid   = (int*)alloc(ET * 4);
    int*   csrc  = (int*)alloc(ET * 4);
    float* cnrm  = (float*)alloc(ET * 4);
    float* Hst   = (float*)alloc((size_t)N_DIM * H_DIM * 4);
    float* Cst   = (float*)alloc((size_t)N_DIM * H_DIM * 4);
    f16*   wfbuf = (f16*)alloc((size_t)8 * 4 * 6 * 64 * 8 * 2);
    float* gbias = (float*)alloc((size_t)N_DIM * 512 * 4);

    // largest Tc dividing 336 whose chunk buffers (rows*256B: h + ah f16) fit
    const int cand[] = {336, 168, 112, 84, 56, 48, 28, 16, 8, 4};
    int Tc = 4;
    for (int i = 0; i < 10; i++) {
        size_t need = off + (size_t)cand[i] * N_DIM * 256 + 4096;
        if (need <= ws_size) { Tc = cand[i]; break; }
    }
    long rows = (long)Tc * N_DIM;
    f16* hbuf  = (f16*)alloc(rows * 128);   // h f16
    f16* ahbuf = (f16*)alloc(rows * 128);   // ah f16

    // --- one-time: CSR build + weight fold/pack + per-node gate bias ---
    k_init<<<(N_DIM + 255) / 256, 256, 0, stream>>>(cnt, fill);
    k_cnt<<<(E_DIM + 255) / 256, 256, 0, stream>>>(ei, cnt);
    k_scan<<<1, 1024, 0, stream>>>(cnt, rowp);
    k_fill<<<(ET + 255) / 256, 256, 0, stream>>>(ei, rowp, fill, eid);
    k_sortdeg<<<(N_DIM + 255) / 256, 256, 0, stream>>>(ew, rowp, eid, dis);
    k_csrmat<<<(N_DIM + 255) / 256, 256, 0, stream>>>(ei, ew, dis, rowp, eid, csrc, cnrm);
    k_wprep<<<48, 256, 0, stream>>>(W2, Wih, Whh, wfbuf);
    k_gbias<<<(int)(((long)N_DIM * 512 + 255) / 256), 256, 0, stream>>>(cb, b2, Wih, bih, bhh, gbias);

    int ntg = (Tc + 3) >> 2;
    long aggWaves = (long)N_DIM * ntg;
    int aggBlocks = (int)((aggWaves + 3) / 4);
    int lblocks   = (N_DIM + 15) / 16;
    int nChunks   = T_DIM / Tc;

    for (int c = 0; c < nChunks; c++) {
        long t0 = (long)c * Tc;
        k_gcn1<<<aggBlocks, 256, 0, stream>>>(x + t0 * N_DIM * FEAT, rowp, csrc, cnrm,
                                              W1, b1, hbuf, Tc);
        k_agg2<<<aggBlocks, 256, 0, stream>>>(hbuf, rowp, csrc, cnrm, ahbuf, Tc);
        k_lstm<<<lblocks, 512, 0, stream>>>(ahbuf, wfbuf, gbias, Wm1, bm1, Wm2, bm2,
                                            Hst, Cst, Tc, c == 0 ? 1 : 0,
                                            c == nChunks - 1 ? 1 : 0, out);
    }
}